// Round 14
// baseline (19.648 us; speedup 1.0000x reference)
//
#include <hip/hip_runtime.h>

// TrafficNetworkDQN fused forward via fp16 MFMA (gfx950).
//
// All layers computed TRANSPOSED:  Act_out[n, m] = W^T[n,k] @ Act_in[k, m] + b[n]
// with positions m on the MFMA *N* dimension: the C/D fragment layout
// (col = lane&15 = m, row = 4*(lane>>4)+reg = n) equals the K=16 B fragment
// layout (k = 4*(lane>>4)+j); K=32 B frag = in-lane concat of two K=16 C/D
// frags (j>=4 -> k+16). Both HW-verified (R3, R8 passes).
//
// R14 = R13 (best known, 19.49us) + s_setprio(1) around each iteration's
// MFMA chain. Waves are not barrier-locked in the loop (they drift after the
// prologue), so a CU holds waves in different phases; setprio lets
// compute-phase waves preempt loader-phase waves for issue slots (T5's
// role-diversity regime, +4-7% on attn). Everything else byte-identical.

#define BL_TOTAL (4096 * 256)

typedef _Float16 half4   __attribute__((ext_vector_type(4)));
typedef _Float16 half8   __attribute__((ext_vector_type(8)));
typedef __fp16   fp16x2  __attribute__((ext_vector_type(2)));
typedef float    floatx4 __attribute__((ext_vector_type(4)));

#define MFMA16(A, B, C) __builtin_amdgcn_mfma_f32_16x16x16f16((A), (B), (C), 0, 0, 0)
#define MFMA32(A, B, C) __builtin_amdgcn_mfma_f32_16x16x32_f16((A), (B), (C), 0, 0, 0)

static __device__ __forceinline__ half4 relu_pack(floatx4 c) {
    fp16x2 lo = __builtin_amdgcn_cvt_pkrtz(c[0], c[1]);
    fp16x2 hi = __builtin_amdgcn_cvt_pkrtz(c[2], c[3]);
    half4 h;
    h[0] = (_Float16)lo[0]; h[1] = (_Float16)lo[1];
    h[2] = (_Float16)hi[0]; h[3] = (_Float16)hi[1];
    return __builtin_elementwise_max(h, (half4)(_Float16)0.0f);
}

static __device__ __forceinline__ half4 pack_rtz(float a, float b, float c, float d) {
    fp16x2 lo = __builtin_amdgcn_cvt_pkrtz(a, b);
    fp16x2 hi = __builtin_amdgcn_cvt_pkrtz(c, d);
    half4 r;
    r[0] = (_Float16)lo[0]; r[1] = (_Float16)lo[1];
    r[2] = (_Float16)hi[0]; r[3] = (_Float16)hi[1];
    return r;
}

static __device__ __forceinline__ half4 pack4_rne(float a, float b, float c, float d) {
    half4 r; r[0] = (_Float16)a; r[1] = (_Float16)b; r[2] = (_Float16)c; r[3] = (_Float16)d;
    return r;
}

static __device__ __forceinline__ half8 cat8(half4 x, half4 y) {
    half8 r;
    r[0] = x[0]; r[1] = x[1]; r[2] = x[2]; r[3] = x[3];
    r[4] = y[0]; r[5] = y[1]; r[6] = y[2]; r[7] = y[3];
    return r;
}

// inputs for one (tileA,tileB) pair, read from LDS
struct InP {
    float a0, a1, a2, a3, b0, b1, b2, b3;
    int sA, sB;
};

static __device__ __forceinline__ InP read_in(
    const float* __restrict__ lfS, const int* __restrict__ ssS,
    int t, int m16, int g)
{
    InP r;
    r.a0 = r.a1 = r.a2 = r.a3 = 0.0f;
    r.b0 = r.b1 = r.b2 = r.b3 = 0.0f;
    const int pA = t * 16 + m16;
    const int pB = pA + 16;
    if (g == 0) {
        const float* q = lfS + pA * 6;
        r.a0 = q[0]; r.a1 = q[1]; r.a2 = q[2]; r.a3 = q[3];
        const float* u = lfS + pB * 6;
        r.b0 = u[0]; r.b1 = u[1]; r.b2 = u[2]; r.b3 = u[3];
    } else if (g == 1) {
        r.a0 = lfS[pA * 6 + 4];
        r.b0 = lfS[pB * 6 + 4];
    }
    r.sA = ssS[pA];
    r.sB = ssS[pB];
    return r;
}

__global__ __launch_bounds__(256, 4) void dqn_mfma(
    const float* __restrict__ lf,    // [BL,5]
    const int*   __restrict__ ss,    // [BL]
    const float* __restrict__ le_w1, const float* __restrict__ le_b1,   // 5x16, 16
    const float* __restrict__ le_w2, const float* __restrict__ le_b2,   // 16x8, 8
    const float* __restrict__ emb,                                      // 8x8
    const float* __restrict__ ls_w1, const float* __restrict__ ls_b1,   // 16x32, 32
    const float* __restrict__ ls_w2, const float* __restrict__ ls_b2,   // 32x16, 16
    const float* __restrict__ ls_w3, const float* __restrict__ ls_b3,   // 16x1, 1
    const float* __restrict__ as_w1, const float* __restrict__ as_b1,   // 16x32, 32
    const float* __restrict__ as_w2, const float* __restrict__ as_b2,   // 32x16, 16
    const float* __restrict__ as_w3, const float* __restrict__ as_b3,   // 16x2, 2
    float* __restrict__ out)         // [BL] scores, then [BL,2] action values
{
    const int lane = threadIdx.x & 63;
    const int wave = threadIdx.x >> 6;
    const int m16  = lane & 15;
    const int g    = lane >> 4;
    const int k0   = g * 4;

    const int tile0 = blockIdx.x * 32 + wave * 8;

    // ---- Phase 0: coalesced load of this wave's ENTIRE input span ----
    const float* src = lf + (long)tile0 * 80;
    float4 va = *reinterpret_cast<const float4*>(src + lane * 10);
    float4 vb = *reinterpret_cast<const float4*>(src + lane * 10 + 4);
    float2 vc = *reinterpret_cast<const float2*>(src + lane * 10 + 8);
    int4 sv = make_int4(0, 0, 0, 0);
    if (lane < 32)
        sv = *reinterpret_cast<const int4*>(ss + tile0 * 16 + lane * 4);

    // ---- LDS pool: frag staging (phase 1) overlaid with inputs (phase 2) ----
    __shared__ floatx4 poolRaw[960];          // 15360 B, 16B-aligned
    __shared__ _Float16 embLDS[64];           // persistent
    half4   (*f4LDS)[64] = reinterpret_cast<half4 (*)[64]>(reinterpret_cast<char*>(poolRaw));
    half8   (*f8LDS)[64] = reinterpret_cast<half8 (*)[64]>(reinterpret_cast<char*>(poolRaw) + 3072);
    floatx4 (*bLDS)[64]  = reinterpret_cast<floatx4 (*)[64]>(reinterpret_cast<char*>(poolRaw) + 6144);

    // ---- Phase 1: cooperative fragment construction (each wave ~1/4) ----
    if (wave == 0) {
        f4LDS[0][lane] = pack4_rne(
            (k0 + 0 < 5) ? le_w1[(k0 + 0) * 16 + m16] : 0.0f,
            (k0 + 1 < 5) ? le_w1[(k0 + 1) * 16 + m16] : 0.0f,
            (k0 + 2 < 5) ? le_w1[(k0 + 2) * 16 + m16] : 0.0f,
            (k0 + 3 < 5) ? le_w1[(k0 + 3) * 16 + m16] : 0.0f);
        f4LDS[4][lane] = pack4_rne(as_w1[(k0+0)*32 + m16],      as_w1[(k0+1)*32 + m16],
                                   as_w1[(k0+2)*32 + m16],      as_w1[(k0+3)*32 + m16]);
        floatx4 b1, b3_2, b5;
        #pragma unroll
        for (int r = 0; r < 4; ++r) {
            b1[r]   = le_b1[4 * g + r];
            b3_2[r] = as_b1[4 * g + r];
            b5[r]   = 0.0f;
        }
        if (g == 0) { b5[0] = ls_b3[0]; b5[1] = as_b3[0]; b5[2] = as_b3[1]; }
        bLDS[0][lane] = b1;
        bLDS[4][lane] = b3_2;
        bLDS[8][lane] = b5;
    } else if (wave == 1) {
        f4LDS[1][lane] = pack4_rne(
            (m16 < 8) ? le_w2[(k0 + 0) * 8 + m16] : 0.0f,
            (m16 < 8) ? le_w2[(k0 + 1) * 8 + m16] : 0.0f,
            (m16 < 8) ? le_w2[(k0 + 2) * 8 + m16] : 0.0f,
            (m16 < 8) ? le_w2[(k0 + 3) * 8 + m16] : 0.0f);
        f4LDS[5][lane] = pack4_rne(as_w1[(k0+0)*32 + 16 + m16], as_w1[(k0+1)*32 + 16 + m16],
                                   as_w1[(k0+2)*32 + 16 + m16], as_w1[(k0+3)*32 + 16 + m16]);
        f8LDS[0][lane] = cat8(
            pack4_rne(ls_w2[(k0+0)*16 + m16],    ls_w2[(k0+1)*16 + m16],
                      ls_w2[(k0+2)*16 + m16],    ls_w2[(k0+3)*16 + m16]),
            pack4_rne(ls_w2[(16+k0+0)*16 + m16], ls_w2[(16+k0+1)*16 + m16],
                      ls_w2[(16+k0+2)*16 + m16], ls_w2[(16+k0+3)*16 + m16]));
        floatx4 b2, b3_3;
        #pragma unroll
        for (int r = 0; r < 4; ++r) {
            b2[r]   = (4 * g + r < 8) ? le_b2[4 * g + r] : 0.0f;
            b3_3[r] = as_b1[16 + 4 * g + r];
        }
        bLDS[1][lane] = b2;
        bLDS[5][lane] = b3_3;
    } else if (wave == 2) {
        f4LDS[2][lane] = pack4_rne(ls_w1[(k0+0)*32 + m16],      ls_w1[(k0+1)*32 + m16],
                                   ls_w1[(k0+2)*32 + m16],      ls_w1[(k0+3)*32 + m16]);
        f8LDS[1][lane] = cat8(
            pack4_rne(as_w2[(k0+0)*16 + m16],    as_w2[(k0+1)*16 + m16],
                      as_w2[(k0+2)*16 + m16],    as_w2[(k0+3)*16 + m16]),
            pack4_rne(as_w2[(16+k0+0)*16 + m16], as_w2[(16+k0+1)*16 + m16],
                      as_w2[(16+k0+2)*16 + m16], as_w2[(16+k0+3)*16 + m16]));
        floatx4 b3_0, b4ls;
        #pragma unroll
        for (int r = 0; r < 4; ++r) {
            b3_0[r] = ls_b1[4 * g + r];
            b4ls[r] = ls_b2[4 * g + r];
        }
        bLDS[2][lane] = b3_0;
        bLDS[6][lane] = b4ls;
    } else {
        f4LDS[3][lane] = pack4_rne(ls_w1[(k0+0)*32 + 16 + m16], ls_w1[(k0+1)*32 + 16 + m16],
                                   ls_w1[(k0+2)*32 + 16 + m16], ls_w1[(k0+3)*32 + 16 + m16]);
        f8LDS[2][lane] = cat8(
            pack4_rne(
                (m16 == 0) ? ls_w3[k0 + 0] : 0.0f,
                (m16 == 0) ? ls_w3[k0 + 1] : 0.0f,
                (m16 == 0) ? ls_w3[k0 + 2] : 0.0f,
                (m16 == 0) ? ls_w3[k0 + 3] : 0.0f),
            pack4_rne(
                (m16 == 1) ? as_w3[(k0+0)*2] : ((m16 == 2) ? as_w3[(k0+0)*2 + 1] : 0.0f),
                (m16 == 1) ? as_w3[(k0+1)*2] : ((m16 == 2) ? as_w3[(k0+1)*2 + 1] : 0.0f),
                (m16 == 1) ? as_w3[(k0+2)*2] : ((m16 == 2) ? as_w3[(k0+2)*2 + 1] : 0.0f),
                (m16 == 1) ? as_w3[(k0+3)*2] : ((m16 == 2) ? as_w3[(k0+3)*2 + 1] : 0.0f)));
        floatx4 b3_1, b4as;
        #pragma unroll
        for (int r = 0; r < 4; ++r) {
            b3_1[r] = ls_b1[16 + 4 * g + r];
            b4as[r] = as_b2[4 * g + r];
        }
        bLDS[3][lane] = b3_1;
        bLDS[7][lane] = b4as;
        embLDS[lane] = (_Float16)emb[lane];
    }
    __syncthreads();

    // ---- per-lane fragment readback ----
    const half4 a1    = f4LDS[0][lane];
    const half4 a2    = f4LDS[1][lane];
    const half4 a3_0  = f4LDS[2][lane];
    const half4 a3_1  = f4LDS[3][lane];
    const half4 a3_2  = f4LDS[4][lane];
    const half4 a3_3  = f4LDS[5][lane];
    const half8 a4ls  = f8LDS[0][lane];
    const half8 a4as  = f8LDS[1][lane];
    const half8 a5    = f8LDS[2][lane];
    const floatx4 bias1   = bLDS[0][lane];
    const floatx4 bias2   = bLDS[1][lane];
    const floatx4 bias3_0 = bLDS[2][lane];
    const floatx4 bias3_1 = bLDS[3][lane];
    const floatx4 bias3_2 = bLDS[4][lane];
    const floatx4 bias3_3 = bLDS[5][lane];
    const floatx4 bias4ls = bLDS[6][lane];
    const floatx4 bias4as = bLDS[7][lane];
    const floatx4 bias5   = bLDS[8][lane];

    // ---- Phase 2: all waves done reading frag staging -> recycle pool ----
    __syncthreads();

    float* lfS = reinterpret_cast<float*>(reinterpret_cast<char*>(poolRaw) + wave * 3584);
    int*   ssS = reinterpret_cast<int*>(reinterpret_cast<char*>(poolRaw) + wave * 3584 + 3072);

    {   // stride-6-float layout (24B/position): conflict-free ds_reads
        float* w0 = lfS + (2 * lane) * 6;
        w0[0] = va.x; w0[1] = va.y; w0[2] = va.z; w0[3] = va.w; w0[4] = vb.x;
        float* w1 = lfS + (2 * lane + 1) * 6;
        w1[0] = vb.y; w1[1] = vb.z; w1[2] = vb.w; w1[3] = vc.x; w1[4] = vc.y;
        if (lane < 32)
            reinterpret_cast<int4*>(ssS)[lane] = sv;
    }

    // ---- main loop: 8 tiles/wave, 2 chains/iter, inputs from LDS (1-ahead) ----
    float* __restrict__ out2 = out + BL_TOTAL;

    InP q0 = read_in(lfS, ssS, 0, m16, g);

    #pragma unroll
    for (int t = 0; t < 8; t += 2) {
        InP q1;
        if (t + 2 < 8) q1 = read_in(lfS, ssS, t + 2, m16, g);

        const int posA = (tile0 + t) * 16 + m16;
        const int posB = posA + 16;

        half4 evA = *reinterpret_cast<const half4*>(&embLDS[q0.sA * 8 + (g & 1) * 4]);
        half4 evB = *reinterpret_cast<const half4*>(&embLDS[q0.sB * 8 + (g & 1) * 4]);

        half4 b1A = pack_rtz(q0.a0, q0.a1, q0.a2, q0.a3);
        half4 b1B = pack_rtz(q0.b0, q0.b1, q0.b2, q0.b3);

        // prioritize the MFMA-chain phase over loader-phase waves (T5)
        __builtin_amdgcn_s_setprio(1);

        // L1: 5->16
        floatx4 c1A = MFMA16(a1, b1A, bias1);
        floatx4 c1B = MFMA16(a1, b1B, bias1);
        half4 h1A = relu_pack(c1A);
        half4 h1B = relu_pack(c1B);

        // L2: 16->8
        floatx4 c2A = MFMA16(a2, h1A, bias2);
        floatx4 c2B = MFMA16(a2, h1B, bias2);
        half4 b3A = relu_pack(c2A);
        half4 b3B = relu_pack(c2B);
        if (g >= 2) { b3A = evA; b3B = evB; }

        // L3: 16->64 (both heads' W1 stacked on n)
        floatx4 c30A = MFMA16(a3_0, b3A, bias3_0);
        floatx4 c30B = MFMA16(a3_0, b3B, bias3_0);
        floatx4 c31A = MFMA16(a3_1, b3A, bias3_1);
        floatx4 c31B = MFMA16(a3_1, b3B, bias3_1);
        floatx4 c32A = MFMA16(a3_2, b3A, bias3_2);
        floatx4 c32B = MFMA16(a3_2, b3B, bias3_2);
        floatx4 c33A = MFMA16(a3_3, b3A, bias3_3);
        floatx4 c33B = MFMA16(a3_3, b3B, bias3_3);
        half4 p0A = relu_pack(c30A), p1A = relu_pack(c31A);
        half4 p2A = relu_pack(c32A), p3A = relu_pack(c33A);
        half4 p0B = relu_pack(c30B), p1B = relu_pack(c31B);
        half4 p2B = relu_pack(c32B), p3B = relu_pack(c33B);

        // L4: 32->16 per head, single K=32 MFMA each
        floatx4 clsA = MFMA32(a4ls, cat8(p0A, p1A), bias4ls);
        floatx4 clsB = MFMA32(a4ls, cat8(p0B, p1B), bias4ls);
        floatx4 casA = MFMA32(a4as, cat8(p2A, p3A), bias4as);
        floatx4 casB = MFMA32(a4as, cat8(p2B, p3B), bias4as);
        half4 hlsA = relu_pack(clsA), hasA = relu_pack(casA);
        half4 hlsB = relu_pack(clsB), hasB = relu_pack(casB);

        // L5: 32->3 (hls||has), single K=32 MFMA
        floatx4 c5A = MFMA32(a5, cat8(hlsA, hasA), bias5);
        floatx4 c5B = MFMA32(a5, cat8(hlsB, hasB), bias5);

        __builtin_amdgcn_s_setprio(0);

        // lane group 0 holds n=0 (score), n=1 (av0), n=2 (av1) for position m16
        if (g == 0) {
            out[posA] = c5A[0];
            out[posB] = c5B[0];
            reinterpret_cast<float2*>(out2)[posA] = make_float2(c5A[1], c5A[2]);
            reinterpret_cast<float2*>(out2)[posB] = make_float2(c5B[1], c5B[2]);
        }

        q0 = q1;
    }
}

extern "C" void kernel_launch(void* const* d_in, const int* in_sizes, int n_in,
                              void* d_out, int out_size, void* d_ws, size_t ws_size,
                              hipStream_t stream) {
    const float* lf    = (const float*)d_in[0];
    const int*   ss    = (const int*)  d_in[1];
    const float* le_w1 = (const float*)d_in[2];
    const float* le_b1 = (const float*)d_in[3];
    const float* le_w2 = (const float*)d_in[4];
    const float* le_b2 = (const float*)d_in[5];
    const float* emb   = (const float*)d_in[6];
    const float* ls_w1 = (const float*)d_in[7];
    const float* ls_b1 = (const float*)d_in[8];
    const float* ls_w2 = (const float*)d_in[9];
    const float* ls_b2 = (const float*)d_in[10];
    const float* ls_w3 = (const float*)d_in[11];
    const float* ls_b3 = (const float*)d_in[12];
    const float* as_w1 = (const float*)d_in[13];
    const float* as_b1 = (const float*)d_in[14];
    const float* as_w2 = (const float*)d_in[15];
    const float* as_b2 = (const float*)d_in[16];
    const float* as_w3 = (const float*)d_in[17];
    const float* as_b3 = (const float*)d_in[18];
    float* out = (float*)d_out;

    // 2048 blocks x 4 waves x 8 tiles x 16 positions = 1,048,576
    dqn_mfma<<<2048, 256, 0, stream>>>(
        lf, ss, le_w1, le_b1, le_w2, le_b2, emb,
        ls_w1, ls_b1, ls_w2, ls_b2, ls_w3, ls_b3,
        as_w1, as_b1, as_w2, as_b2, as_w3, as_b3,
        out);
}

// Round 15
// 19.380 us; speedup vs baseline: 1.0138x; 1.0138x over previous
//
#include <hip/hip_runtime.h>

// TrafficNetworkDQN fused forward via fp16 MFMA (gfx950).
//
// All layers computed TRANSPOSED:  Act_out[n, m] = W^T[n,k] @ Act_in[k, m] + b[n]
// with positions m on the MFMA *N* dimension: the C/D fragment layout
// (col = lane&15 = m, row = 4*(lane>>4)+reg = n) equals the K=16 B fragment
// layout (k = 4*(lane>>4)+j); K=32 B frag = in-lane concat of two K=16 C/D
// frags (j>=4 -> k+16). Both HW-verified (R3, R8 passes).
//
// R15 = R13 body with a single-cohort grid: 1024 blocks x 4 waves x 16
// tiles/wave (exactly 4 blocks/CU -> whole grid co-resident; no mid-kernel
// cohort drain/refill; prologue paid once per 16 tiles instead of 8).
// Input staging doubled to 7KB/wave in the recycled LDS pool; phase-0 loads
// are now 16B-aligned (5 x float4 + int4 per lane). R12's inverse result
// (more blocks -> -10%) motivates fewer, longer blocks.

#define BL_TOTAL (4096 * 256)

typedef _Float16 half4   __attribute__((ext_vector_type(4)));
typedef _Float16 half8   __attribute__((ext_vector_type(8)));
typedef __fp16   fp16x2  __attribute__((ext_vector_type(2)));
typedef float    floatx4 __attribute__((ext_vector_type(4)));

#define MFMA16(A, B, C) __builtin_amdgcn_mfma_f32_16x16x16f16((A), (B), (C), 0, 0, 0)
#define MFMA32(A, B, C) __builtin_amdgcn_mfma_f32_16x16x32_f16((A), (B), (C), 0, 0, 0)

static __device__ __forceinline__ half4 relu_pack(floatx4 c) {
    fp16x2 lo = __builtin_amdgcn_cvt_pkrtz(c[0], c[1]);
    fp16x2 hi = __builtin_amdgcn_cvt_pkrtz(c[2], c[3]);
    half4 h;
    h[0] = (_Float16)lo[0]; h[1] = (_Float16)lo[1];
    h[2] = (_Float16)hi[0]; h[3] = (_Float16)hi[1];
    return __builtin_elementwise_max(h, (half4)(_Float16)0.0f);
}

static __device__ __forceinline__ half4 pack_rtz(float a, float b, float c, float d) {
    fp16x2 lo = __builtin_amdgcn_cvt_pkrtz(a, b);
    fp16x2 hi = __builtin_amdgcn_cvt_pkrtz(c, d);
    half4 r;
    r[0] = (_Float16)lo[0]; r[1] = (_Float16)lo[1];
    r[2] = (_Float16)hi[0]; r[3] = (_Float16)hi[1];
    return r;
}

static __device__ __forceinline__ half4 pack4_rne(float a, float b, float c, float d) {
    half4 r; r[0] = (_Float16)a; r[1] = (_Float16)b; r[2] = (_Float16)c; r[3] = (_Float16)d;
    return r;
}

static __device__ __forceinline__ half8 cat8(half4 x, half4 y) {
    half8 r;
    r[0] = x[0]; r[1] = x[1]; r[2] = x[2]; r[3] = x[3];
    r[4] = y[0]; r[5] = y[1]; r[6] = y[2]; r[7] = y[3];
    return r;
}

// inputs for one (tileA,tileB) pair, read from LDS
struct InP {
    float a0, a1, a2, a3, b0, b1, b2, b3;
    int sA, sB;
};

static __device__ __forceinline__ InP read_in(
    const float* __restrict__ lfS, const int* __restrict__ ssS,
    int t, int m16, int g)
{
    InP r;
    r.a0 = r.a1 = r.a2 = r.a3 = 0.0f;
    r.b0 = r.b1 = r.b2 = r.b3 = 0.0f;
    const int pA = t * 16 + m16;
    const int pB = pA + 16;
    if (g == 0) {
        const float* q = lfS + pA * 6;
        r.a0 = q[0]; r.a1 = q[1]; r.a2 = q[2]; r.a3 = q[3];
        const float* u = lfS + pB * 6;
        r.b0 = u[0]; r.b1 = u[1]; r.b2 = u[2]; r.b3 = u[3];
    } else if (g == 1) {
        r.a0 = lfS[pA * 6 + 4];
        r.b0 = lfS[pB * 6 + 4];
    }
    r.sA = ssS[pA];
    r.sB = ssS[pB];
    return r;
}

__global__ __launch_bounds__(256, 4) void dqn_mfma(
    const float* __restrict__ lf,    // [BL,5]
    const int*   __restrict__ ss,    // [BL]
    const float* __restrict__ le_w1, const float* __restrict__ le_b1,   // 5x16, 16
    const float* __restrict__ le_w2, const float* __restrict__ le_b2,   // 16x8, 8
    const float* __restrict__ emb,                                      // 8x8
    const float* __restrict__ ls_w1, const float* __restrict__ ls_b1,   // 16x32, 32
    const float* __restrict__ ls_w2, const float* __restrict__ ls_b2,   // 32x16, 16
    const float* __restrict__ ls_w3, const float* __restrict__ ls_b3,   // 16x1, 1
    const float* __restrict__ as_w1, const float* __restrict__ as_b1,   // 16x32, 32
    const float* __restrict__ as_w2, const float* __restrict__ as_b2,   // 32x16, 16
    const float* __restrict__ as_w3, const float* __restrict__ as_b3,   // 16x2, 2
    float* __restrict__ out)         // [BL] scores, then [BL,2] action values
{
    const int lane = threadIdx.x & 63;
    const int wave = threadIdx.x >> 6;
    const int m16  = lane & 15;
    const int g    = lane >> 4;
    const int k0   = g * 4;

    const int tile0 = blockIdx.x * 64 + wave * 16;   // 16 tiles per wave

    // ---- Phase 0: coalesced load of this wave's ENTIRE input span ----
    // 256 positions x 5 floats = 1280 floats; lane l owns positions
    // 4l..4l+3 (floats [l*20, l*20+20), 16B-aligned).
    const float* src = lf + (long)tile0 * 80;
    float4 v0 = *reinterpret_cast<const float4*>(src + lane * 20 + 0);
    float4 v1 = *reinterpret_cast<const float4*>(src + lane * 20 + 4);
    float4 v2 = *reinterpret_cast<const float4*>(src + lane * 20 + 8);
    float4 v3 = *reinterpret_cast<const float4*>(src + lane * 20 + 12);
    float4 v4 = *reinterpret_cast<const float4*>(src + lane * 20 + 16);
    int4 sv = *reinterpret_cast<const int4*>(ss + tile0 * 16 + lane * 4);

    // ---- LDS pool: frag staging (phase 1, 15360B) overlaid with inputs
    //      (phase 2, 4 waves x 7168B = 28672B) ----
    __shared__ floatx4 poolRaw[1792];         // 28672 B, 16B-aligned
    __shared__ _Float16 embLDS[64];           // persistent
    half4   (*f4LDS)[64] = reinterpret_cast<half4 (*)[64]>(reinterpret_cast<char*>(poolRaw));
    half8   (*f8LDS)[64] = reinterpret_cast<half8 (*)[64]>(reinterpret_cast<char*>(poolRaw) + 3072);
    floatx4 (*bLDS)[64]  = reinterpret_cast<floatx4 (*)[64]>(reinterpret_cast<char*>(poolRaw) + 6144);

    // ---- Phase 1: cooperative fragment construction (each wave ~1/4) ----
    if (wave == 0) {
        f4LDS[0][lane] = pack4_rne(
            (k0 + 0 < 5) ? le_w1[(k0 + 0) * 16 + m16] : 0.0f,
            (k0 + 1 < 5) ? le_w1[(k0 + 1) * 16 + m16] : 0.0f,
            (k0 + 2 < 5) ? le_w1[(k0 + 2) * 16 + m16] : 0.0f,
            (k0 + 3 < 5) ? le_w1[(k0 + 3) * 16 + m16] : 0.0f);
        f4LDS[4][lane] = pack4_rne(as_w1[(k0+0)*32 + m16],      as_w1[(k0+1)*32 + m16],
                                   as_w1[(k0+2)*32 + m16],      as_w1[(k0+3)*32 + m16]);
        floatx4 b1, b3_2, b5;
        #pragma unroll
        for (int r = 0; r < 4; ++r) {
            b1[r]   = le_b1[4 * g + r];
            b3_2[r] = as_b1[4 * g + r];
            b5[r]   = 0.0f;
        }
        if (g == 0) { b5[0] = ls_b3[0]; b5[1] = as_b3[0]; b5[2] = as_b3[1]; }
        bLDS[0][lane] = b1;
        bLDS[4][lane] = b3_2;
        bLDS[8][lane] = b5;
    } else if (wave == 1) {
        f4LDS[1][lane] = pack4_rne(
            (m16 < 8) ? le_w2[(k0 + 0) * 8 + m16] : 0.0f,
            (m16 < 8) ? le_w2[(k0 + 1) * 8 + m16] : 0.0f,
            (m16 < 8) ? le_w2[(k0 + 2) * 8 + m16] : 0.0f,
            (m16 < 8) ? le_w2[(k0 + 3) * 8 + m16] : 0.0f);
        f4LDS[5][lane] = pack4_rne(as_w1[(k0+0)*32 + 16 + m16], as_w1[(k0+1)*32 + 16 + m16],
                                   as_w1[(k0+2)*32 + 16 + m16], as_w1[(k0+3)*32 + 16 + m16]);
        f8LDS[0][lane] = cat8(
            pack4_rne(ls_w2[(k0+0)*16 + m16],    ls_w2[(k0+1)*16 + m16],
                      ls_w2[(k0+2)*16 + m16],    ls_w2[(k0+3)*16 + m16]),
            pack4_rne(ls_w2[(16+k0+0)*16 + m16], ls_w2[(16+k0+1)*16 + m16],
                      ls_w2[(16+k0+2)*16 + m16], ls_w2[(16+k0+3)*16 + m16]));
        floatx4 b2, b3_3;
        #pragma unroll
        for (int r = 0; r < 4; ++r) {
            b2[r]   = (4 * g + r < 8) ? le_b2[4 * g + r] : 0.0f;
            b3_3[r] = as_b1[16 + 4 * g + r];
        }
        bLDS[1][lane] = b2;
        bLDS[5][lane] = b3_3;
    } else if (wave == 2) {
        f4LDS[2][lane] = pack4_rne(ls_w1[(k0+0)*32 + m16],      ls_w1[(k0+1)*32 + m16],
                                   ls_w1[(k0+2)*32 + m16],      ls_w1[(k0+3)*32 + m16]);
        f8LDS[1][lane] = cat8(
            pack4_rne(as_w2[(k0+0)*16 + m16],    as_w2[(k0+1)*16 + m16],
                      as_w2[(k0+2)*16 + m16],    as_w2[(k0+3)*16 + m16]),
            pack4_rne(as_w2[(16+k0+0)*16 + m16], as_w2[(16+k0+1)*16 + m16],
                      as_w2[(16+k0+2)*16 + m16], as_w2[(16+k0+3)*16 + m16]));
        floatx4 b3_0, b4ls;
        #pragma unroll
        for (int r = 0; r < 4; ++r) {
            b3_0[r] = ls_b1[4 * g + r];
            b4ls[r] = ls_b2[4 * g + r];
        }
        bLDS[2][lane] = b3_0;
        bLDS[6][lane] = b4ls;
    } else {
        f4LDS[3][lane] = pack4_rne(ls_w1[(k0+0)*32 + 16 + m16], ls_w1[(k0+1)*32 + 16 + m16],
                                   ls_w1[(k0+2)*32 + 16 + m16], ls_w1[(k0+3)*32 + 16 + m16]);
        f8LDS[2][lane] = cat8(
            pack4_rne(
                (m16 == 0) ? ls_w3[k0 + 0] : 0.0f,
                (m16 == 0) ? ls_w3[k0 + 1] : 0.0f,
                (m16 == 0) ? ls_w3[k0 + 2] : 0.0f,
                (m16 == 0) ? ls_w3[k0 + 3] : 0.0f),
            pack4_rne(
                (m16 == 1) ? as_w3[(k0+0)*2] : ((m16 == 2) ? as_w3[(k0+0)*2 + 1] : 0.0f),
                (m16 == 1) ? as_w3[(k0+1)*2] : ((m16 == 2) ? as_w3[(k0+1)*2 + 1] : 0.0f),
                (m16 == 1) ? as_w3[(k0+2)*2] : ((m16 == 2) ? as_w3[(k0+2)*2 + 1] : 0.0f),
                (m16 == 1) ? as_w3[(k0+3)*2] : ((m16 == 2) ? as_w3[(k0+3)*2 + 1] : 0.0f)));
        floatx4 b3_1, b4as;
        #pragma unroll
        for (int r = 0; r < 4; ++r) {
            b3_1[r] = ls_b1[16 + 4 * g + r];
            b4as[r] = as_b2[4 * g + r];
        }
        bLDS[3][lane] = b3_1;
        bLDS[7][lane] = b4as;
        embLDS[lane] = (_Float16)emb[lane];
    }
    __syncthreads();

    // ---- per-lane fragment readback ----
    const half4 a1    = f4LDS[0][lane];
    const half4 a2    = f4LDS[1][lane];
    const half4 a3_0  = f4LDS[2][lane];
    const half4 a3_1  = f4LDS[3][lane];
    const half4 a3_2  = f4LDS[4][lane];
    const half4 a3_3  = f4LDS[5][lane];
    const half8 a4ls  = f8LDS[0][lane];
    const half8 a4as  = f8LDS[1][lane];
    const half8 a5    = f8LDS[2][lane];
    const floatx4 bias1   = bLDS[0][lane];
    const floatx4 bias2   = bLDS[1][lane];
    const floatx4 bias3_0 = bLDS[2][lane];
    const floatx4 bias3_1 = bLDS[3][lane];
    const floatx4 bias3_2 = bLDS[4][lane];
    const floatx4 bias3_3 = bLDS[5][lane];
    const floatx4 bias4ls = bLDS[6][lane];
    const floatx4 bias4as = bLDS[7][lane];
    const floatx4 bias5   = bLDS[8][lane];

    // ---- Phase 2: all waves done reading frag staging -> recycle pool ----
    __syncthreads();

    float* lfS = reinterpret_cast<float*>(reinterpret_cast<char*>(poolRaw) + wave * 7168);
    int*   ssS = reinterpret_cast<int*>(reinterpret_cast<char*>(poolRaw) + wave * 7168 + 6144);

    {   // stride-6-float layout (24B/position); lane owns positions 4l..4l+3
        float* w = lfS + (4 * lane) * 6;
        w[0]  = v0.x; w[1]  = v0.y; w[2]  = v0.z; w[3]  = v0.w; w[4]  = v1.x;   // pos 4l
        w[6]  = v1.y; w[7]  = v1.z; w[8]  = v1.w; w[9]  = v2.x; w[10] = v2.y;   // pos 4l+1
        w[12] = v2.z; w[13] = v2.w; w[14] = v3.x; w[15] = v3.y; w[16] = v3.z;   // pos 4l+2
        w[18] = v3.w; w[19] = v4.x; w[20] = v4.y; w[21] = v4.z; w[22] = v4.w;   // pos 4l+3
        reinterpret_cast<int4*>(ssS)[lane] = sv;
    }

    // ---- main loop: 16 tiles/wave, 2 chains/iter, inputs from LDS (1-ahead) ----
    float* __restrict__ out2 = out + BL_TOTAL;

    InP q0 = read_in(lfS, ssS, 0, m16, g);

    #pragma unroll
    for (int t = 0; t < 16; t += 2) {
        InP q1;
        if (t + 2 < 16) q1 = read_in(lfS, ssS, t + 2, m16, g);

        const int posA = (tile0 + t) * 16 + m16;
        const int posB = posA + 16;

        half4 evA = *reinterpret_cast<const half4*>(&embLDS[q0.sA * 8 + (g & 1) * 4]);
        half4 evB = *reinterpret_cast<const half4*>(&embLDS[q0.sB * 8 + (g & 1) * 4]);

        half4 b1A = pack_rtz(q0.a0, q0.a1, q0.a2, q0.a3);
        half4 b1B = pack_rtz(q0.b0, q0.b1, q0.b2, q0.b3);

        // L1: 5->16
        floatx4 c1A = MFMA16(a1, b1A, bias1);
        floatx4 c1B = MFMA16(a1, b1B, bias1);
        half4 h1A = relu_pack(c1A);
        half4 h1B = relu_pack(c1B);

        // L2: 16->8
        floatx4 c2A = MFMA16(a2, h1A, bias2);
        floatx4 c2B = MFMA16(a2, h1B, bias2);
        half4 b3A = relu_pack(c2A);
        half4 b3B = relu_pack(c2B);
        if (g >= 2) { b3A = evA; b3B = evB; }

        // L3: 16->64 (both heads' W1 stacked on n)
        floatx4 c30A = MFMA16(a3_0, b3A, bias3_0);
        floatx4 c30B = MFMA16(a3_0, b3B, bias3_0);
        floatx4 c31A = MFMA16(a3_1, b3A, bias3_1);
        floatx4 c31B = MFMA16(a3_1, b3B, bias3_1);
        floatx4 c32A = MFMA16(a3_2, b3A, bias3_2);
        floatx4 c32B = MFMA16(a3_2, b3B, bias3_2);
        floatx4 c33A = MFMA16(a3_3, b3A, bias3_3);
        floatx4 c33B = MFMA16(a3_3, b3B, bias3_3);
        half4 p0A = relu_pack(c30A), p1A = relu_pack(c31A);
        half4 p2A = relu_pack(c32A), p3A = relu_pack(c33A);
        half4 p0B = relu_pack(c30B), p1B = relu_pack(c31B);
        half4 p2B = relu_pack(c32B), p3B = relu_pack(c33B);

        // L4: 32->16 per head, single K=32 MFMA each
        floatx4 clsA = MFMA32(a4ls, cat8(p0A, p1A), bias4ls);
        floatx4 clsB = MFMA32(a4ls, cat8(p0B, p1B), bias4ls);
        floatx4 casA = MFMA32(a4as, cat8(p2A, p3A), bias4as);
        floatx4 casB = MFMA32(a4as, cat8(p2B, p3B), bias4as);
        half4 hlsA = relu_pack(clsA), hasA = relu_pack(casA);
        half4 hlsB = relu_pack(clsB), hasB = relu_pack(casB);

        // L5: 32->3 (hls||has), single K=32 MFMA
        floatx4 c5A = MFMA32(a5, cat8(hlsA, hasA), bias5);
        floatx4 c5B = MFMA32(a5, cat8(hlsB, hasB), bias5);

        // lane group 0 holds n=0 (score), n=1 (av0), n=2 (av1) for position m16
        if (g == 0) {
            out[posA] = c5A[0];
            out[posB] = c5B[0];
            reinterpret_cast<float2*>(out2)[posA] = make_float2(c5A[1], c5A[2]);
            reinterpret_cast<float2*>(out2)[posB] = make_float2(c5B[1], c5B[2]);
        }

        q0 = q1;
    }
}

extern "C" void kernel_launch(void* const* d_in, const int* in_sizes, int n_in,
                              void* d_out, int out_size, void* d_ws, size_t ws_size,
                              hipStream_t stream) {
    const float* lf    = (const float*)d_in[0];
    const int*   ss    = (const int*)  d_in[1];
    const float* le_w1 = (const float*)d_in[2];
    const float* le_b1 = (const float*)d_in[3];
    const float* le_w2 = (const float*)d_in[4];
    const float* le_b2 = (const float*)d_in[5];
    const float* emb   = (const float*)d_in[6];
    const float* ls_w1 = (const float*)d_in[7];
    const float* ls_b1 = (const float*)d_in[8];
    const float* ls_w2 = (const float*)d_in[9];
    const float* ls_b2 = (const float*)d_in[10];
    const float* ls_w3 = (const float*)d_in[11];
    const float* ls_b3 = (const float*)d_in[12];
    const float* as_w1 = (const float*)d_in[13];
    const float* as_b1 = (const float*)d_in[14];
    const float* as_w2 = (const float*)d_in[15];
    const float* as_b2 = (const float*)d_in[16];
    const float* as_w3 = (const float*)d_in[17];
    const float* as_b3 = (const float*)d_in[18];
    float* out = (float*)d_out;

    // 1024 blocks x 4 waves x 16 tiles x 16 positions = 1,048,576
    dqn_mfma<<<1024, 256, 0, stream>>>(
        lf, ss, le_w1, le_b1, le_w2, le_b2, emb,
        ls_w1, ls_b1, ls_w2, ls_b2, ls_w3, ls_b3,
        as_w1, as_b1, as_w2, as_b2, as_w3, as_b3,
        out);
}